// Round 10
// baseline (497.907 us; speedup 1.0000x reference)
//
#include <hip/hip_runtime.h>

// GRU fused, round 16: latency-chain cuts on the r14/r15 base.
// r15's null (removing issue work didn't move the wall) proves the step is
// dependency-latency bound: ~850 cyc/step with ~160 issue. Cuts here:
//  1. revert merged-rcp (r15 lengthened the r-chain; r14 form is shortest).
//  2. MFMA partials: aXa=mfma(.,B0,0) || aXb=mfma(.,B1,0), fold the add
//     into act input -> chain loses one MFMA latency.
//  3. service x FIFO depth 3 (slack ~2500 cyc >> 900 HBM latency) -> the
//     borderline 1-step slack no longer stalls the barrier each step.
// Keeps: 3 gate + 1 service waves, XB-elimination (gi rides B1), early
// half-write, CSTR=36 layout. Fragment mappings = validated r10/r11/r14.

typedef _Float16 f16x8 __attribute__((ext_vector_type(8)));
typedef float f32x4 __attribute__((ext_vector_type(4)));
typedef __fp16 h2_t __attribute__((ext_vector_type(2)));

namespace {

constexpr int T  = 1024;
constexpr int DM = 6;
constexpr int H  = 48;
constexpr int NB = 16;     // batches per block
constexpr int CSTR = 36;   // dwords/col: pairs 0-23 h, 24-26 x, 27 (1,0),
                           // 28-31 zeros, 32-35 pad.

constexpr float SRZ = -1.44269504088896340736f;  // -log2(e): sigmoid arg
constexpr float SN  =  2.88539008177792681472f;  // 2*log2(e): tanh arg

__device__ __forceinline__ float fexp2(float x) { return __builtin_amdgcn_exp2f(x); }
__device__ __forceinline__ float frcp(float x) { return __builtin_amdgcn_rcpf(x); }
__device__ __forceinline__ unsigned pk(float a, float b) {   // RTZ (weights/x)
  union { h2_t h; unsigned u; } r; r.h = __builtin_amdgcn_cvt_pkrtz(a, b); return r.u;
}
__device__ __forceinline__ unsigned pk_rtn(float a, float b) {  // RTN (h state)
  union { __fp16 h[2]; unsigned u; } r; r.h[0] = (__fp16)a; r.h[1] = (__fp16)b; return r.u;
}

union F8 { unsigned u[4]; f16x8 v; };

// fused K-column: kk<48 -> W_hh row; 48..53 -> W_ih row (x slots); 54 -> bias.
__device__ __forceinline__ float kv48(const float* Wrow, const float* IHrow,
                                      float bias, int kk) {
  if (kk < 48) return Wrow ? Wrow[kk] : 0.0f;
  if (kk < 54) return IHrow ? IHrow[kk - 48] : 0.0f;
  if (kk == 54) return bias;
  return 0.0f;
}

// Barrier draining LDS only: global loads/stores stay in flight.
__device__ __forceinline__ void bar_lgkm() {
  asm volatile("s_waitcnt lgkmcnt(0)\n\ts_barrier" ::: "memory");
}

__global__ __launch_bounds__(256)
void gru_mfma6(
    const float* __restrict__ x, const float* __restrict__ W_ih,
    const float* __restrict__ W_hh, const float* __restrict__ b_ih,
    const float* __restrict__ b_hh, const float* __restrict__ fc_w,
    const float* __restrict__ fc_b, float* __restrict__ y) {

  // [buf][col*CSTR + pair]; pair p of col c = rows (2p,2p+1), even row low.
  __shared__ __align__(16) unsigned hbuf[2][16 * CSTR];

  const int tid = threadIdx.x;
  const int wid = tid >> 6;        // 0..2 gate tiles, 3 = service (x + FC)
  const int l   = tid & 63;
  const int c   = l & 15;          // batch col (B/C/D) and M-row (A)
  const int q   = l >> 4;          // lane quad
  const size_t bb = (size_t)blockIdx.x * NB;
  const bool isSvc = (wid == 3);

  // ---- loop-invariant A fragments ----
  F8 aR0, aR1, aZ0, aZ1, aG0, aG1, aGI;   // gate waves
  F8 aFC0, aFC1;                          // service wave
  if (!isSvc) {
    const int rrow = wid * 16 + c;
    const int zrow = 48 + wid * 16 + c;
    const int nrow = 96 + wid * 16 + c;
    const float* wr = W_hh + rrow * H; const float* ir  = W_ih + rrow * DM;
    const float* wz = W_hh + zrow * H; const float* iz  = W_ih + zrow * DM;
    const float* wn = W_hh + nrow * H; const float* in_ = W_ih + nrow * DM;
    const float bs = b_ih[rrow] + b_hh[rrow];
    const float bz = b_ih[zrow] + b_hh[zrow];
    const float bh = b_hh[nrow], bi = b_ih[nrow];
#pragma unroll
    for (int w = 0; w < 4; ++w) {
      const int k0 = 8 * q + 2 * w;
      aR0.u[w] = pk(SRZ * wr[k0], SRZ * wr[k0 + 1]);
      aZ0.u[w] = pk(SRZ * wz[k0], SRZ * wz[k0 + 1]);
      aG0.u[w] = pk(SN * wn[k0], SN * wn[k0 + 1]);
      aR1.u[w] = pk(SRZ * kv48(wr, ir, bs, 32 + k0), SRZ * kv48(wr, ir, bs, 33 + k0));
      aZ1.u[w] = pk(SRZ * kv48(wz, iz, bz, 32 + k0), SRZ * kv48(wz, iz, bz, 33 + k0));
      aG1.u[w] = pk(SN * kv48(wn, nullptr, bh, 32 + k0), SN * kv48(wn, nullptr, bh, 33 + k0));
      // gi for n-gate rides B1: A-slots at chunk-1 k 48..54 (q==2 lanes).
      const int kc = 32 + k0;
      auto gv = [&](int k) -> float {
        if (k >= 48 && k < 54) return SN * in_[k - 48];
        if (k == 54) return SN * bi;
        return 0.0f;
      };
      aGI.u[w] = (q == 2) ? pk(gv(kc), gv(kc + 1)) : 0u;
    }
  } else {
    const bool vr = (c < DM);
    const float* wr = vr ? (fc_w + c * H) : nullptr;
    const float fb = vr ? fc_b[c] : 0.0f;
#pragma unroll
    for (int w = 0; w < 4; ++w) {
      const int k0 = 8 * q + 2 * w;
      aFC0.u[w] = wr ? pk(wr[k0], wr[k0 + 1]) : 0u;
      aFC1.u[w] = pk(kv48(wr, nullptr, fb, 32 + k0), kv48(wr, nullptr, fb, 33 + k0));
    }
  }

  // ---- LDS init: zero everything, BARRIER, then payload stores ----
  for (int i = tid; i < 2 * 16 * CSTR; i += 256) ((unsigned*)hbuf)[i] = 0u;
  __syncthreads();

  if (tid < 32) hbuf[tid >> 4][(tid & 15) * CSTR + 27] = 0x00003C00u;  // (1.0, 0)

  // service wave x-pipeline: lane ll<48 owns col=ll/3, dword dw=ll%3.
  // FIFO depth 3: fx0=x[s+1], fx1=x[s+2], fx2=x[s+3] at entry of step s.
  const int ll = (l < 48) ? l : 47;
  const int xcol = ll / 3, xdw = ll - 3 * xcol;
  const float* xptr = x + (bb + xcol) * (size_t)(T * DM) + 2 * xdw;
  const int xwr = xcol * CSTR + 24 + xdw;
  float2 fx0 = {0, 0}, fx1 = {0, 0}, fx2 = {0, 0};
  if (isSvc) {
    const float2 v0 = *(const float2*)xptr;                  // x[0]
    if (l < 48) hbuf[0][xwr] = pk(v0.x, v0.y);
    fx0 = *(const float2*)(xptr + DM);                       // x[1]
    fx1 = *(const float2*)(xptr + 2 * DM);                   // x[2]
    fx2 = *(const float2*)(xptr + 3 * DM);                   // x[3]
  }

  float* yp = y + (bb + c) * (size_t)(T * DM);
  const f32x4 z4 = {0.0f, 0.0f, 0.0f, 0.0f};
  float hf[4] = {0.0f, 0.0f, 0.0f, 0.0f};  // rows 16wid+4q+j, col c

  const int rd0 = c * CSTR + 4 * q;        // B0: pairs 4q..4q+3  (k 8q..8q+7)
  const int rd1 = c * CSTR + 16 + 4 * q;   // B1: h32-47 | x | (1,0) | zeros
  const int wr_ = c * CSTR + 8 * wid + 2 * q;

  __syncthreads();

  auto STEP = [&](const unsigned* hb, unsigned* hn, int s) {
    if (!isSvc) {
      F8 B0, B1;
      const uint4 h0 = *(const uint4*)&hb[rd0];
      const uint4 h1 = *(const uint4*)&hb[rd1];
      B0.u[0] = h0.x; B0.u[1] = h0.y; B0.u[2] = h0.z; B0.u[3] = h0.w;
      B1.u[0] = h1.x; B1.u[1] = h1.y; B1.u[2] = h1.z; B1.u[3] = h1.w;

      // independent partials: no MFMA->MFMA dependency
      f32x4 aRa = __builtin_amdgcn_mfma_f32_16x16x32_f16(aR0.v, B0.v, z4, 0, 0, 0);
      f32x4 aRb = __builtin_amdgcn_mfma_f32_16x16x32_f16(aR1.v, B1.v, z4, 0, 0, 0);
      f32x4 aZa = __builtin_amdgcn_mfma_f32_16x16x32_f16(aZ0.v, B0.v, z4, 0, 0, 0);
      f32x4 aZb = __builtin_amdgcn_mfma_f32_16x16x32_f16(aZ1.v, B1.v, z4, 0, 0, 0);
      f32x4 aGa = __builtin_amdgcn_mfma_f32_16x16x32_f16(aG0.v, B0.v, z4, 0, 0, 0);
      f32x4 aGb = __builtin_amdgcn_mfma_f32_16x16x32_f16(aG1.v, B1.v, z4, 0, 0, 0);
      f32x4 aI  = __builtin_amdgcn_mfma_f32_16x16x32_f16(aGI.v, B1.v, z4, 0, 0, 0);

#pragma unroll
      for (int j = 0; j < 4; ++j) {
        const float r_ = frcp(1.0f + fexp2(aRa[j] + aRb[j]));
        const float z_ = frcp(1.0f + fexp2(aZa[j] + aZb[j]));
        const float u_ = frcp(fexp2(fmaf(r_, aGa[j] + aGb[j], aI[j])) + 1.0f);
        const float n_ = fmaf(-2.0f, u_, 1.0f);              // tanh
        hf[j] = fmaf(z_, hf[j] - n_, n_);                    // n + z*(h-n)
        if (j == 1) hn[wr_] = pk_rtn(hf[0], hf[1]);          // early half-write
      }
      hn[wr_ + 1] = pk_rtn(hf[2], hf[3]);
    } else {
      // FC: y[s-1] from h[s-1] (this read buffer)
      F8 B0, B1;
      const uint4 h0 = *(const uint4*)&hb[rd0];
      const uint4 h1 = *(const uint4*)&hb[rd1];
      B0.u[0] = h0.x; B0.u[1] = h0.y; B0.u[2] = h0.z; B0.u[3] = h0.w;
      B1.u[0] = h1.x; B1.u[1] = h1.y; B1.u[2] = h1.z; B1.u[3] = h1.w;
      f32x4 ya = __builtin_amdgcn_mfma_f32_16x16x32_f16(aFC0.v, B0.v, z4, 0, 0, 0);
      ya = __builtin_amdgcn_mfma_f32_16x16x32_f16(aFC1.v, B1.v, ya, 0, 0, 0);
      if (s > 0) {
        if (q == 0) {
          float2 s0 = {ya[0], ya[1]}, s1 = {ya[2], ya[3]};
          *(float2*)(yp + (s - 1) * DM) = s0;
          *(float2*)(yp + (s - 1) * DM + 2) = s1;
        } else if (q == 1) {
          float2 sv = {ya[0], ya[1]};
          *(float2*)(yp + (s - 1) * DM + 4) = sv;
        }
      }
      // commit x[s+1] (fx0), rotate FIFO, issue x[s+4]
      if (l < 48) hn[xwr] = pk(fx0.x, fx0.y);
      fx0 = fx1; fx1 = fx2;
      const int tn = (s + 4 < T) ? (s + 4) : (T - 1);
      fx2 = *(const float2*)(xptr + tn * DM);
    }
    bar_lgkm();
  };

#pragma unroll 1
  for (int s2 = 0; s2 < T; s2 += 2) {
    STEP(&hbuf[0][0], &hbuf[1][0], s2);
    STEP(&hbuf[1][0], &hbuf[0][0], s2 + 1);
  }

  // epilogue: y[T-1] from h[T-1] (in hbuf[0]; last barrier already passed)
  if (isSvc) {
    const unsigned* hb = &hbuf[0][0];
    F8 B0, B1;
    const uint4 h0 = *(const uint4*)&hb[rd0];
    const uint4 h1 = *(const uint4*)&hb[rd1];
    B0.u[0] = h0.x; B0.u[1] = h0.y; B0.u[2] = h0.z; B0.u[3] = h0.w;
    B1.u[0] = h1.x; B1.u[1] = h1.y; B1.u[2] = h1.z; B1.u[3] = h1.w;
    f32x4 ya = __builtin_amdgcn_mfma_f32_16x16x32_f16(aFC0.v, B0.v, z4, 0, 0, 0);
    ya = __builtin_amdgcn_mfma_f32_16x16x32_f16(aFC1.v, B1.v, ya, 0, 0, 0);
    if (q == 0) {
      float2 s0 = {ya[0], ya[1]}, s1 = {ya[2], ya[3]};
      *(float2*)(yp + (T - 1) * DM) = s0;
      *(float2*)(yp + (T - 1) * DM + 2) = s1;
    } else if (q == 1) {
      float2 sv = {ya[0], ya[1]};
      *(float2*)(yp + (T - 1) * DM + 4) = sv;
    }
  }
}

}  // namespace

extern "C" void kernel_launch(void* const* d_in, const int* in_sizes, int n_in,
                              void* d_out, int out_size, void* d_ws, size_t ws_size,
                              hipStream_t stream) {
  const float* x    = (const float*)d_in[0];
  const float* W_ih = (const float*)d_in[1];
  const float* W_hh = (const float*)d_in[2];
  const float* b_ih = (const float*)d_in[3];
  const float* b_hh = (const float*)d_in[4];
  const float* fc_w = (const float*)d_in[5];
  const float* fc_b = (const float*)d_in[6];
  float* y = (float*)d_out;

  constexpr int B = 2048;
  gru_mfma6<<<B / NB, 256, 0, stream>>>(x, W_ih, W_hh, b_ih, b_hh, fc_w, fc_b, y);
}